// Round 15
// baseline (250.914 us; speedup 1.0000x reference)
//
#include <hip/hip_runtime.h>
#include <cstdint>
#include <cstddef>

typedef short s8v __attribute__((ext_vector_type(8)));
typedef short s4v __attribute__((ext_vector_type(4)));
typedef float f4v __attribute__((ext_vector_type(4)));

static __device__ __forceinline__ float b2f(short s){
  return __uint_as_float(((uint32_t)(uint16_t)s) << 16);
}
static __device__ __forceinline__ short f2bf(float f){
  uint32_t u = __float_as_uint(f);
  u = (u + 0x7fffu + ((u >> 16) & 1u)) >> 16;
  return (short)(uint16_t)u;
}

// ---- graph prep (fused) ----
__global__ void k_deg(const int* __restrict__ tgt, int* __restrict__ deg, int nE){
  int e = blockIdx.x*blockDim.x + threadIdx.x;
  if(e < nE) atomicAdd(&deg[tgt[e]], 1);
}

#define SCAN_BS 256
__global__ void k_scan1_dinv(const int* __restrict__ deg, int* __restrict__ rowptr,
                             int* __restrict__ blocksum, float* __restrict__ dinv, int nN){
  __shared__ int tmp[SCAN_BS];
  const int t = threadIdx.x;
  const int i = blockIdx.x*SCAN_BS + t;
  int v = (i < nN) ? deg[i] : 0;
  if(i < nN) dinv[i] = rsqrtf((float)v + 1.0f);   // +1 self-loop
  tmp[t] = v; __syncthreads();
  #pragma unroll
  for(int off=1; off<SCAN_BS; off<<=1){
    int x = (t >= off) ? tmp[t-off] : 0;
    __syncthreads();
    tmp[t] += x;
    __syncthreads();
  }
  if(i < nN) rowptr[i] = tmp[t] - v;
  if(t == SCAN_BS-1) blocksum[blockIdx.x] = tmp[t];
}
__global__ void k_scan2_bounds(int* __restrict__ blocksum, int nb,
                               const int* __restrict__ batch, int* __restrict__ gstart,
                               int nN, int nG){
  __shared__ int tmp[1024];
  const int t = threadIdx.x;
  int v = (t < nb) ? blocksum[t] : 0;
  tmp[t] = v; __syncthreads();
  #pragma unroll
  for(int off=1; off<1024; off<<=1){
    int x = (t >= off) ? tmp[t-off] : 0;
    __syncthreads();
    tmp[t] += x;
    __syncthreads();
  }
  if(t < nb) blocksum[t] = tmp[t] - v;
  if(t <= nG){
    int lo = 0, hi = nN;
    while(lo < hi){
      int mid = (lo + hi) >> 1;
      if(batch[mid] < t) lo = mid + 1; else hi = mid;
    }
    gstart[t] = lo;
  }
}
__global__ void k_scan3(int* __restrict__ rowptr, const int* __restrict__ blocksum,
                        int nN, int nE){
  const int i = blockIdx.x*SCAN_BS + threadIdx.x;
  if(i < nN) rowptr[i] += blocksum[blockIdx.x];
  if(i == 0) rowptr[nN] = nE;
}
__global__ void k_fill(const int* __restrict__ src, const int* __restrict__ tgt,
                       const int* __restrict__ rowptr, int* __restrict__ cursor,
                       int* __restrict__ csr_src, float* __restrict__ csr_w,
                       const float* __restrict__ dinv, int nE){
  int e = blockIdx.x*blockDim.x + threadIdx.x;
  if(e >= nE) return;
  int t = tgt[e];
  int s = src[e];
  int pos = rowptr[t] + atomicAdd(&cursor[t], 1);
  csr_src[pos] = s;
  csr_w[pos] = dinv[s] * dinv[t];
}
__global__ void k_transpose_cvt2(const float* __restrict__ W1, short* __restrict__ W1T,
                                 int K1, const float* __restrict__ W2, short* __restrict__ W2T,
                                 int K2, int N){
  int g = blockIdx.x*blockDim.x + threadIdx.x;
  const int t1 = K1*N;
  if(g < t1){
    int n = g / K1, k = g % K1;
    W1T[(size_t)n*K1 + k] = f2bf(W1[(size_t)k*N + n]);
  } else {
    g -= t1;
    if(g >= K2*N) return;
    int n = g / K2, k = g % K2;
    W2T[(size_t)n*K2 + k] = f2bf(W2[(size_t)k*N + n]);
  }
}

// ---- streaming GEMM: 128 x 256 tile (full-N), reg-staged T14, NBUF=2 ----
// C[m][n] = sum_k A[m][k]*Bt[n][k], N = 256 (full width in one block pass).
// Logical-traffic-minimal: A streamed exactly ONCE (single column pass),
// B staged (M/128) x 384KB. 256 thr (4 waves); wave wv owns rows
// [wv*32, wv*32+32), all 256 cols: acc[2][16].
// Schedule per iter kc: compute(kc) | vmcnt(0) (loads(kc+1) landed, hidden
// under compute) | ds_write(kc+1) | issue loads(kc+2) | lgkmcnt(0)+barrier.
// Loads for kc+2 stay in flight across the barrier (no vmcnt at barrier).
// NBUF=2 safety: writes to slot (kc+1)&1 occur strictly between barrier(kc)
// and barrier(kc+1), where all waves read slot kc&1 only.
template<bool AF32>
__global__ __launch_bounds__(256) void gemm_stream(const void* __restrict__ Ap,
    const short* __restrict__ Bt, short* __restrict__ C, int M, int N, int K)
{
  __shared__ __align__(16) short As[2][128*32];   // 8 KB per buf
  __shared__ __align__(16) short Bs[2][256*32];   // 16 KB per buf
  const int tid  = threadIdx.x;
  const int lane = tid & 63;
  const int wv   = tid >> 6;
  const int lr   = lane & 15;
  const int hi   = lane >> 4;
  const int blk_row = blockIdx.x * 128;
  const int nkc = K / 32;

  f4v acc[2][16];
  #pragma unroll
  for(int s=0;s<2;s++)
    #pragma unroll
    for(int nf=0;nf<16;nf++){ acc[s][nf][0]=0.f; acc[s][nf][1]=0.f; acc[s][nf][2]=0.f; acc[s][nf][3]=0.f; }

  // staging regs
  f4v ar[4];            // A f32
  s8v ab2[2];           // A bf16
  s8v br[4];            // B (256 rows, 4 steps of 16 rows)

  auto LOAD = [&](int kc){
    if constexpr(AF32){
      #pragma unroll
      for(int j=0;j<4;j++){
        const int lrow = wv*32 + j*8 + (lane>>3);
        int grow = blk_row + lrow; if(grow >= M) grow = M-1;
        ar[j] = *(const f4v*)((const char*)Ap + ((size_t)grow*K + (size_t)kc*32)*4 + ((lane&7)<<4));
      }
    } else {
      #pragma unroll
      for(int j=0;j<2;j++){
        const int lrow = wv*32 + j*16 + (lane>>2);
        int grow = blk_row + lrow; if(grow >= M) grow = M-1;
        ab2[j] = *(const s8v*)((const char*)Ap + ((size_t)grow*K + (size_t)kc*32)*2 + ((lane&3)<<4));
      }
    }
    #pragma unroll
    for(int j=0;j<4;j++){
      const int lrow = wv*64 + j*16 + (lane>>2);   // B col index 0..255
      br[j] = *(const s8v*)((const char*)Bt + ((size_t)lrow*K + (size_t)kc*32)*2 + ((lane&3)<<4));
    }
  };
  auto WRITE = [&](int buf){
    if constexpr(AF32){
      #pragma unroll
      for(int j=0;j<4;j++){
        const int lrow = wv*32 + j*8 + (lane>>3);
        const int sl = lane & 7;
        const int c = (sl>>1) ^ ((lrow>>1)&3);
        s4v v;
        #pragma unroll
        for(int q=0;q<4;q++) v[q] = f2bf(ar[j][q]);
        *(s4v*)(&As[buf][lrow*32 + c*8 + (sl&1)*4]) = v;
      }
    } else {
      #pragma unroll
      for(int j=0;j<2;j++){
        const int lrow = wv*32 + j*16 + (lane>>2);
        const int c = (lane&3) ^ ((lrow>>1)&3);
        *(s8v*)(&As[buf][lrow*32 + c*8]) = ab2[j];
      }
    }
    #pragma unroll
    for(int j=0;j<4;j++){
      const int lrow = wv*64 + j*16 + (lane>>2);
      const int c = (lane&3) ^ ((lrow>>1)&3);
      *(s8v*)(&Bs[buf][lrow*32 + c*8]) = br[j];
    }
  };

  // prologue
  LOAD(0);
  asm volatile("s_waitcnt vmcnt(0)" ::: "memory");
  WRITE(0);
  if(nkc > 1) LOAD(1);
  asm volatile("s_waitcnt lgkmcnt(0)" ::: "memory");
  __builtin_amdgcn_s_barrier();
  __builtin_amdgcn_sched_barrier(0);

  for(int kc=0; kc<nkc; kc++){
    const char* ab = (const char*)&As[kc&1][0];
    const char* bb = (const char*)&Bs[kc&1][0];

    s8v a[2];
    #pragma unroll
    for(int s=0;s<2;s++){
      const int row = wv*32 + s*16 + lr;
      const int c = hi ^ ((row>>1) & 3);
      a[s] = *(const s8v*)(ab + row*64 + (c<<4));
    }
    #pragma unroll
    for(int nf=0;nf<16;nf++){
      const int brow = nf*16 + lr;
      const int c = hi ^ ((brow>>1) & 3);
      s8v bfr = *(const s8v*)(bb + brow*64 + (c<<4));
      acc[0][nf] = __builtin_amdgcn_mfma_f32_16x16x32_bf16(a[0], bfr, acc[0][nf], 0, 0, 0);
      acc[1][nf] = __builtin_amdgcn_mfma_f32_16x16x32_bf16(a[1], bfr, acc[1][nf], 0, 0, 0);
    }

    if(kc+1 < nkc){
      asm volatile("s_waitcnt vmcnt(0)" ::: "memory");   // loads(kc+1) landed
      WRITE((kc+1)&1);
      if(kc+2 < nkc) LOAD(kc+2);                          // in flight across barrier
    }
    asm volatile("s_waitcnt lgkmcnt(0)" ::: "memory");
    __builtin_amdgcn_s_barrier();
    __builtin_amdgcn_sched_barrier(0);
  }

  #pragma unroll
  for(int s=0;s<2;s++){
    #pragma unroll
    for(int j=0;j<4;j++){
      const int row = blk_row + wv*32 + s*16 + hi*4 + j;
      if(row >= M) continue;
      #pragma unroll
      for(int nf=0;nf<16;nf++){
        const int col = nf*16 + lr;
        C[(size_t)row*N + col] = f2bf(acc[s][nf][j]);
      }
    }
  }
}

// ---- fused aggregation: one wave per node, coalesced idx/weight prefetch + 8-deep gather ----
__global__ __launch_bounds__(256) void k_aggregate(
    const short* __restrict__ h, const float* __restrict__ dinv,
    const int* __restrict__ rowptr, const int* __restrict__ csr_src,
    const float* __restrict__ csr_w, const float* __restrict__ bias,
    short* __restrict__ hout, int nN)
{
  const int wave = threadIdx.x >> 6;
  const int lane = threadIdx.x & 63;
  const int node = blockIdx.x*4 + wave;
  if(node >= nN) return;
  const float di = dinv[node];
  const int beg = rowptr[node];
  const int deg = rowptr[node+1] - beg;

  s4v hv = *(const s4v*)&h[(size_t)node*256 + lane*4];
  const float d2 = di*di;
  f4v acc;
  #pragma unroll
  for(int j=0;j<4;j++) acc[j] = d2 * b2f(hv[j]);

  for(int base=0; base<deg; base+=64){
    const int cnt = min(deg - base, 64);
    int   myi = (lane < cnt) ? csr_src[beg + base + lane] : 0;
    float myw = (lane < cnt) ? csr_w[beg + base + lane] : 0.f;

    for(int p0=0; p0<cnt; p0+=8){
      s4v v[8]; float w[8]; int s[8];
      #pragma unroll
      for(int j=0;j<8;j++){
        int pp = p0 + j;
        int sl = (pp < cnt) ? pp : 0;
        s[j] = __shfl(myi, sl);
        w[j] = (pp < cnt) ? __shfl(myw, sl) : 0.f;
      }
      #pragma unroll
      for(int j=0;j<8;j++)
        v[j] = *(const s4v*)&h[(size_t)s[j]*256 + lane*4];
      #pragma unroll
      for(int j=0;j<8;j++){
        #pragma unroll
        for(int q=0;q<4;q++) acc[q] += w[j] * b2f(v[j][q]);
      }
    }
  }

  f4v bv = *(const f4v*)&bias[lane*4];
  s4v ov;
  #pragma unroll
  for(int j=0;j<4;j++) ov[j] = f2bf(fmaxf(acc[j]+bv[j], 0.f));
  *(s4v*)&hout[(size_t)node*256 + lane*4] = ov;
}

// ---- mean-pool: per-(graph,slice) partial sums, no atomics, no memset ----
#define POOL_SPLIT 8
__global__ __launch_bounds__(256) void k_pool(const short* __restrict__ h,
    const int* __restrict__ gstart, float* __restrict__ pool, int nG){
  const int g = blockIdx.x;
  const int sl = blockIdx.y;
  const int c = threadIdx.x;
  const int b = gstart[g], e = gstart[g+1];
  const int len = e - b;
  const int r0 = b + (int)((long long)len * sl / POOL_SPLIT);
  const int r1 = b + (int)((long long)len * (sl+1) / POOL_SPLIT);
  float acc = 0.f;
  for(int r=r0; r<r1; r++) acc += b2f(h[(size_t)r*256 + c]);
  pool[((size_t)g*POOL_SPLIT + sl)*256 + c] = acc;
}

__global__ void k_final(const float* __restrict__ pool, const int* __restrict__ gstart,
                        const float* __restrict__ Wp, const float* __restrict__ bp,
                        float* __restrict__ out, int HID_, int OUT_){
  __shared__ float mean[256];
  int g = blockIdx.x, j = threadIdx.x;
  float c = fmaxf((float)(gstart[g+1] - gstart[g]), 1.0f);
  for(int k=j; k<HID_; k+=blockDim.x){
    float s = 0.f;
    #pragma unroll
    for(int sl=0; sl<POOL_SPLIT; sl++)
      s += pool[((size_t)g*POOL_SPLIT + sl)*HID_ + k];
    mean[k] = s / c;
  }
  __syncthreads();
  float acc = bp[j];
  for(int k=0;k<HID_;k++) acc = fmaf(mean[k], Wp[(size_t)k*OUT_ + j], acc);
  out[(size_t)g*OUT_ + j] = acc;
}

extern "C" void kernel_launch(void* const* d_in, const int* in_sizes, int n_in,
                              void* d_out, int out_size, void* d_ws, size_t ws_size,
                              hipStream_t stream){
  const float* x   = (const float*)d_in[0];
  const int* ei    = (const int*)d_in[1];
  const int* batch = (const int*)d_in[2];
  const float* W1  = (const float*)d_in[3];
  const float* b1  = (const float*)d_in[4];
  const float* W2  = (const float*)d_in[5];
  const float* b2  = (const float*)d_in[6];
  const float* Wp  = (const float*)d_in[7];
  const float* bp  = (const float*)d_in[8];
  float* out = (float*)d_out;

  const int HID    = in_sizes[4];            // 256
  const int IN_DIM = in_sizes[3] / HID;      // 768
  const int OUT    = in_sizes[8];            // 128
  const int nE     = in_sizes[1] / 2;        // 300000
  const int nN     = in_sizes[2];            // 50000
  const int nG     = out_size / OUT;         // 64

  const int* src = ei;
  const int* tgt = ei + nE;

  char* w = (char*)d_ws;
  size_t off = 0;
  auto alloc = [&](size_t bytes)->char*{
    char* p = w + off; off += (bytes + 511) & ~(size_t)511; return p;
  };
  int*   deg     = (int*)  alloc((size_t)nN*4);      // deg+cursor adjacent: one memset
  int*   cursor  = (int*)  alloc((size_t)nN*4);
  float* dinv    = (float*)alloc((size_t)nN*4);
  int*   gstart  = (int*)  alloc((size_t)(nG+1)*4);
  float* pool    = (float*)alloc((size_t)nG*POOL_SPLIT*HID*4);
  int*   rowptr  = (int*)  alloc((size_t)(nN+1)*4);
  int*   csr_src = (int*)  alloc((size_t)nE*4);
  float* csr_w   = (float*)alloc((size_t)nE*4);
  int*   blocksum= (int*)  alloc((size_t)1024*4);
  short* W1T     = (short*)alloc((size_t)IN_DIM*HID*2);
  short* W2T     = (short*)alloc((size_t)HID*HID*2);
  short* h1      = (short*)alloc((size_t)(nN+128)*HID*2);
  short* h2      = (short*)alloc((size_t)(nN+128)*HID*2);
  (void)ws_size; (void)n_in;

  hipMemsetAsync(deg, 0, (size_t)((char*)cursor - (char*)deg) + (size_t)nN*4, stream);

  const int nb = (nN + SCAN_BS - 1) / SCAN_BS;
  k_deg <<<(nE+255)/256, 256, 0, stream>>>(tgt, deg, nE);
  k_scan1_dinv<<<nb, SCAN_BS, 0, stream>>>(deg, rowptr, blocksum, dinv, nN);
  k_scan2_bounds<<<1, 1024, 0, stream>>>(blocksum, nb, batch, gstart, nN, nG);
  k_scan3<<<nb, SCAN_BS, 0, stream>>>(rowptr, blocksum, nN, nE);
  k_fill <<<(nE+255)/256, 256, 0, stream>>>(src, tgt, rowptr, cursor, csr_src, csr_w, dinv, nE);
  k_transpose_cvt2<<<((IN_DIM+HID)*HID+255)/256, 256, 0, stream>>>(W1, W1T, IN_DIM, W2, W2T, HID, HID);

  const int ngb = (nN + 127) / 128;
  const int nagg = (nN + 3) / 4;
  // layer 1 (f32 A, converted in staging regs; A streamed exactly once)
  gemm_stream<true><<<ngb, 256, 0, stream>>>(x, W1T, h2, nN, HID, IN_DIM);
  k_aggregate<<<nagg, 256, 0, stream>>>(h2, dinv, rowptr, csr_src, csr_w, b1, h1, nN);
  // layer 2 (bf16 A)
  gemm_stream<false><<<ngb, 256, 0, stream>>>(h1, W2T, h2, nN, HID, HID);
  k_aggregate<<<nagg, 256, 0, stream>>>(h2, dinv, rowptr, csr_src, csr_w, b2, h1, nN);
  k_pool<<<dim3(nG, POOL_SPLIT), 256, 0, stream>>>(h1, gstart, pool, nG);
  // head
  k_final<<<nG, OUT, 0, stream>>>(pool, gstart, Wp, bp, out, HID, OUT);
}